// Round 7
// baseline (304.088 us; speedup 1.0000x reference)
//
#include <hip/hip_runtime.h>
#include <hip/hip_bf16.h>

typedef __attribute__((ext_vector_type(4))) float f32x4;
typedef __attribute__((ext_vector_type(8))) short s16x8;
typedef __attribute__((ext_vector_type(4))) short s16x4;
typedef unsigned short u16;

// ---- helpers -------------------------------------------------------------

__device__ __forceinline__ f32x4 mfma16(s16x8 a, s16x8 b, f32x4 c) {
    return __builtin_amdgcn_mfma_f32_16x16x32_bf16(a, b, c, 0, 0, 0);
}

// K=16 bf16 MFMA (PV step). Fallback: zero-padded K=32 (identical math).
__device__ __forceinline__ f32x4 mfma_k16(s16x4 a, s16x4 b, f32x4 c) {
#if __has_builtin(__builtin_amdgcn_mfma_f32_16x16x16bf16_1k)
    return __builtin_amdgcn_mfma_f32_16x16x16bf16_1k(a, b, c, 0, 0, 0);
#else
    s16x8 a8 = { a[0], a[1], a[2], a[3], 0, 0, 0, 0 };
    s16x8 b8 = { b[0], b[1], b[2], b[3], 0, 0, 0, 0 };
    return __builtin_amdgcn_mfma_f32_16x16x32_bf16(a8, b8, c, 0, 0, 0);
#endif
}

// RNE fp32 -> bf16 (bit trick)
__device__ __forceinline__ u16 bf(float f) {
    union { float f; unsigned u; } x; x.f = f;
    return (u16)((x.u + 0x7fffu + ((x.u >> 16) & 1u)) >> 16);
}
__device__ __forceinline__ unsigned pkbf(float a, float b) {
    union { float f; unsigned u; } x, y; x.f = a; y.f = b;
    unsigned ra = x.u + 0x7fffu + ((x.u >> 16) & 1u);
    unsigned rb = y.u + 0x7fffu + ((y.u >> 16) & 1u);
    return (ra >> 16) | (rb & 0xffff0000u);
}

// async global->LDS, 16B per lane (wave-uniform LDS base + lane*16)
__device__ __forceinline__ void gl_lds16(const u16* g, u16* l) {
    __builtin_amdgcn_global_load_lds(
        (const __attribute__((address_space(1))) unsigned*)g,
        (__attribute__((address_space(3))) unsigned*)l, 16, 0, 0);
}

// ---- K0: merged fp32 -> bf16 convert (x, Wq, Wk, Wv, Wo in one launch) ---

__global__ __launch_bounds__(256) void cvt_all_kernel(
        const float* __restrict__ x,  const float* __restrict__ Wq,
        const float* __restrict__ Wk, const float* __restrict__ Wv,
        const float* __restrict__ Wo,
        u16* __restrict__ xb, u16* __restrict__ wb, u16* __restrict__ wob) {
    int i = blockIdx.x * 256 + threadIdx.x;
    const float* src; u16* dst; int off;
    if (i < 1048576)      { src = x;  dst = xb;            off = i; }
    else if (i < 1310720) { src = Wq; dst = wb;            off = i - 1048576; }
    else if (i < 1572864) { src = Wk; dst = wb + 1048576;  off = i - 1310720; }
    else if (i < 1835008) { src = Wv; dst = wb + 2097152;  off = i - 1572864; }
    else if (i < 1851392) { src = Wo; dst = wob;           off = i - 1835008; }
    else return;
    f32x4 v = ((const f32x4*)src)[off];
    union { s16x4 v; unsigned u[2]; } r;
    r.u[0] = pkbf(v.x, v.y);
    r.u[1] = pkbf(v.z, v.w);
    ((s16x4*)dst)[off] = r.v;
}

// ---- K1: QKV projections, m97-style LDS-staged 128x128 GEMM -------------

__global__ __launch_bounds__(256, 3) void qkv_kernel(
        const u16* __restrict__ xb, const u16* __restrict__ wb,
        const float* __restrict__ bq, const float* __restrict__ bk,
        const float* __restrict__ bv,
        u16* __restrict__ qo, u16* __restrict__ kTo, u16* __restrict__ vTo) {
    __shared__ u16 As[128 * 32];
    __shared__ u16 Bs[128 * 32];
    int bx   = blockIdx.x % 24;
    int by   = blockIdx.x / 24;
    int tid  = threadIdx.x;
    int lane = tid & 63, w = tid >> 6;
    int l15  = lane & 15, quad = lane >> 4;
    int wr   = w >> 1, wc = w & 1;

    const u16* Ag = xb + (size_t)(by * 128 + (tid >> 2)) * 1024 + (tid & 3) * 8;
    const u16* Bg = wb + (size_t)(bx * 128 + (tid >> 2)) * 1024 + (tid & 3) * 8;
    u16* Al = As + tid * 8;
    u16* Bl = Bs + tid * 8;

    const u16* abase = As + (wr * 64 + l15) * 32 + quad * 8;
    const u16* bbase = Bs + (wc * 64 + l15) * 32 + quad * 8;

    f32x4 acc[4][4] = {};
    for (int k0 = 0; k0 < 1024; k0 += 32) {
        gl_lds16(Ag + k0, Al);
        gl_lds16(Ag + 64 * 1024 + k0, Al + 64 * 32);
        gl_lds16(Bg + k0, Bl);
        gl_lds16(Bg + 64 * 1024 + k0, Bl + 64 * 32);
        __syncthreads();
        s16x8 a[4], b[4];
#pragma unroll
        for (int mi = 0; mi < 4; mi++) a[mi] = *(const s16x8*)(abase + mi * 16 * 32);
#pragma unroll
        for (int nj = 0; nj < 4; nj++) b[nj] = *(const s16x8*)(bbase + nj * 16 * 32);
#pragma unroll
        for (int mi = 0; mi < 4; mi++)
#pragma unroll
            for (int nj = 0; nj < 4; nj++) acc[mi][nj] = mfma16(a[mi], b[nj], acc[mi][nj]);
        __syncthreads();
    }

    int fblk = (bx * 128 + wc * 64) >> 6;
    int mat  = fblk >> 4, h = fblk & 15;
    const float* bias = (mat == 0) ? bq : (mat == 1 ? bk : bv);
#pragma unroll
    for (int nj = 0; nj < 4; nj++) {
        int e = nj * 16 + l15;
        float bb = bias[h * 64 + e];
#pragma unroll
        for (int mi = 0; mi < 4; mi++) {
            int n0 = by * 128 + wr * 64 + mi * 16 + quad * 4;
            f32x4 c = acc[mi][nj];
            if (mat == 0) {
                u16* p = qo + ((size_t)h * 4096 + n0) * 64 + e;
#pragma unroll
                for (int r = 0; r < 4; r++) p[(size_t)r * 64] = bf(c[r] + bb);
            } else {
                u16* p = (mat == 1 ? kTo : vTo) + ((size_t)h * 64 + e) * 4096 + n0;
                union { s16x4 v; u16 s[4]; } pk;
#pragma unroll
                for (int r = 0; r < 4; r++) pk.s[r] = bf(c[r] + bb);
                *(s16x4*)p = pk.v;
            }
        }
    }
}

// ---- K2: kp/vp — round-5 config, split across TWO dispatches (ks0=0,8) --
// grid per dispatch: 512 blocks; b = ((p*16+h)*2 + jt)*8 + ksl.
// block: M=128 (j), N=64 (e), K-chunk=256 in 8 stages of BK=32.

__global__ __launch_bounds__(256, 4) void kpvp_kernel(
        const float* __restrict__ Ew, const float* __restrict__ Fw,
        const u16* __restrict__ kT, const u16* __restrict__ vT,
        float* __restrict__ accs, int ks0) {
    __shared__ u16 As[128 * 40];   // 10 KB (pitch 40 u16 = conflict-free)
    __shared__ u16 Bs[64 * 32];    // 4 KB
    int b    = blockIdx.x;
    int ks   = (b & 7) + ks0, jt = (b >> 3) & 1, h = (b >> 4) & 15, p = b >> 8;
    int tid  = threadIdx.x;
    int lane = tid & 63, w = tid >> 6;
    int l15  = lane & 15, quad = lane >> 4;
    int wm   = w & 1, wn = w >> 1;

    const float* Ag = (p ? Fw : Ew)
        + (size_t)(h * 256 + jt * 128 + (tid >> 3)) * 4096 + ks * 256 + (tid & 7) * 4;
    const u16* Bg = (p ? vT : kT)
        + ((size_t)h * 64 + (tid >> 2)) * 4096 + ks * 256 + (tid & 3) * 8;
    u16* Aw = As + (tid >> 3) * 40 + (tid & 7) * 4;
    u16* Bl = Bs + tid * 8;

    const u16* abase = As + (wm * 64 + l15) * 40 + quad * 8;
    const u16* bbase = Bs + (wn * 32 + l15) * 32 + quad * 8;

    f32x4 acc[4][2] = {};
    for (int s = 0; s < 8; s++) {
        int kk = s * 32;
        gl_lds16(Bg + kk, Bl);
#pragma unroll
        for (int pr = 0; pr < 4; pr++) {
            f32x4 v = *(const f32x4*)(Ag + (size_t)pr * 32 * 4096 + kk);
            union { s16x4 q; unsigned u[2]; } rr;
            rr.u[0] = pkbf(v.x, v.y);
            rr.u[1] = pkbf(v.z, v.w);
            *(s16x4*)(Aw + pr * 32 * 40) = rr.q;
        }
        __syncthreads();
        s16x8 a[4], bb2[2];
#pragma unroll
        for (int mt = 0; mt < 4; mt++) a[mt] = *(const s16x8*)(abase + mt * 16 * 40);
#pragma unroll
        for (int nt = 0; nt < 2; nt++) bb2[nt] = *(const s16x8*)(bbase + nt * 16 * 32);
#pragma unroll
        for (int mt = 0; mt < 4; mt++)
#pragma unroll
            for (int nt = 0; nt < 2; nt++)
                acc[mt][nt] = mfma16(a[mt], bb2[nt], acc[mt][nt]);
        __syncthreads();
    }

    size_t base = (size_t)ks * 524288
        + ((size_t)(p * 16 + h) * 256 + jt * 128 + wm * 64 + quad * 4) * 64
        + wn * 32 + l15;
#pragma unroll
    for (int mt = 0; mt < 4; mt++)
#pragma unroll
        for (int nt = 0; nt < 2; nt++)
#pragma unroll
            for (int r = 0; r < 4; r++)
                accs[base + (size_t)(mt * 16 + r) * 64 + nt * 16] = acc[mt][nt][r];
}

// ---- K3: reduce 16 slices + bias + pack (coalesced; LDS transpose for vp)
// grid: 256 blocks; b: p = b>>7, h = (b>>3)&15, j0 = (b&7)*32.

__global__ __launch_bounds__(256) void packkv_kernel(
        const float* __restrict__ accs, const float* __restrict__ Eb,
        const float* __restrict__ Fb, u16* __restrict__ kp, u16* __restrict__ vpT) {
    __shared__ u16 tile[32 * 72];
    int b  = blockIdx.x;
    int p  = b >> 7, h = (b >> 3) & 15, j0 = (b & 7) * 32;
    int t  = threadIdx.x;
    int jr = t >> 3, ec = (t & 7) * 8;

    size_t base = ((size_t)(p * 16 + h) * 256 + j0 + jr) * 64 + ec;
    float v[8] = {};
#pragma unroll
    for (int s = 0; s < 16; s++) {
        f32x4 lo = *(const f32x4*)(accs + base + (size_t)s * 524288);
        f32x4 hi = *(const f32x4*)(accs + base + (size_t)s * 524288 + 4);
#pragma unroll
        for (int i = 0; i < 4; i++) { v[i] += lo[i]; v[i + 4] += hi[i]; }
    }
    float bias = p ? Fb[h * 256 + j0 + jr] : Eb[h * 256 + j0 + jr];
    float scale = p ? 1.0f : 0.125f;      // fold 1/sqrt(64) into kp
    union { s16x8 o; unsigned u[4]; } pk;
#pragma unroll
    for (int i = 0; i < 4; i++)
        pk.u[i] = pkbf((v[2 * i] + bias) * scale, (v[2 * i + 1] + bias) * scale);

    if (p == 0) {
        *(s16x8*)(kp + ((size_t)(h * 256 + j0 + jr)) * 64 + ec) = pk.o;
    } else {
        *(s16x8*)(tile + jr * 72 + ec) = pk.o;
        __syncthreads();
        int er = t >> 2, jc = (t & 3) * 8;
        union { s16x8 o; u16 s[8]; } tr;
#pragma unroll
        for (int i = 0; i < 8; i++) tr.s[i] = tile[(jc + i) * 72 + er];
        *(s16x8*)(vpT + ((size_t)(h * 64 + er)) * 256 + j0 + jc) = tr.o;
    }
}

// ---- K4: attention — transposed scores, in-register softmax, K=16 PV ----
// No LDS, no barriers. grid: h*64 + bm; 4 independent waves x 16 n-rows.

__global__ __launch_bounds__(256) void attn_kernel(
        const u16* __restrict__ q, const u16* __restrict__ kp,
        const u16* __restrict__ vpT, u16* __restrict__ zs) {
    int bm   = blockIdx.x & 63, h = blockIdx.x >> 6;
    int lane = threadIdx.x & 63, w = threadIdx.x >> 6;
    int l15  = lane & 15, quad = lane >> 4;
    int nbase = bm * 64 + w * 16;

    // S^T tile: s[jt] rows j = jt*16 + quad*4 + r, col n = nbase + l15.
    // A = kp (j x e), B = q (n x e); scale pre-folded into kp.
    f32x4 s[16] = {};
    const u16* qp  = q  + ((size_t)h * 4096 + nbase + l15) * 64 + quad * 8;
    const u16* kpp = kp + ((size_t)h * 256 + l15) * 64 + quad * 8;
#pragma unroll
    for (int e0 = 0; e0 < 64; e0 += 32) {
        s16x8 bq = *(const s16x8*)(qp + e0);
#pragma unroll
        for (int jt = 0; jt < 16; jt++) {
            s16x8 aq = *(const s16x8*)(kpp + jt * 16 * 64 + e0);
            s[jt] = mfma16(aq, bq, s[jt]);
        }
    }

    // softmax over j for this lane's n: 64 regs + cross-quad shfl(16,32)
    float m = s[0][0];
#pragma unroll
    for (int jt = 0; jt < 16; jt++)
#pragma unroll
        for (int r = 0; r < 4; r++) m = fmaxf(m, s[jt][r]);
    m = fmaxf(m, __shfl_xor(m, 16));
    m = fmaxf(m, __shfl_xor(m, 32));
    float l = 0.f;
#pragma unroll
    for (int jt = 0; jt < 16; jt++)
#pragma unroll
        for (int r = 0; r < 4; r++) {
            float pv = __expf(s[jt][r] - m);
            s[jt][r] = pv;
            l += pv;
        }
    l += __shfl_xor(l, 16);
    l += __shfl_xor(l, 32);
    float inv = 1.0f / l;

    // PV via K=16 MFMA: a-frag = normalized P (already A-layout), b from vpT
    f32x4 z[4] = {};
    const u16* vb = vpT + (size_t)h * 64 * 256 + l15 * 256 + quad * 4;
#pragma unroll
    for (int jt = 0; jt < 16; jt++) {
        union { s16x4 v; unsigned u[2]; } a;
        a.u[0] = pkbf(s[jt][0] * inv, s[jt][1] * inv);
        a.u[1] = pkbf(s[jt][2] * inv, s[jt][3] * inv);
#pragma unroll
        for (int et = 0; et < 4; et++) {
            s16x4 bv = *(const s16x4*)(vb + (size_t)et * 16 * 256 + jt * 16);
            z[et] = mfma_k16(a.v, bv, z[et]);
        }
    }

    // z: C layout: n = nbase + quad*4 + r, e = et*16 + l15
#pragma unroll
    for (int et = 0; et < 4; et++) {
        int e = et * 16 + l15;
        u16* o = zs + ((size_t)(nbase + quad * 4)) * 1024 + h * 64 + e;
#pragma unroll
        for (int r = 0; r < 4; r++) o[(size_t)r * 1024] = bf(z[et][r]);
    }
}

// ---- K5: out = zs @ Wo^T, split-K=4, disjoint slices (no atomics) -------

__global__ __launch_bounds__(256) void out_kernel(
        const u16* __restrict__ zs, const u16* __restrict__ wob,
        float* __restrict__ oslice) {
    int ks   = blockIdx.x & 3;
    int bm   = blockIdx.x >> 2;
    int lane = threadIdx.x & 63, w = threadIdx.x >> 6;
    int l15  = lane & 15, quad = lane >> 4;
    int row0 = bm * 128 + w * 32;

    const u16* A = zs  + (size_t)(row0 + l15) * 1024 + ks * 256 + quad * 8;
    const u16* B = wob + (size_t)l15 * 1024 + ks * 256 + quad * 8;

    f32x4 acc[2][4] = {};
    for (int k = 0; k < 256; k += 32) {
        s16x8 a0 = *(const s16x8*)(A + k);
        s16x8 a1 = *(const s16x8*)(A + 16 * 1024 + k);
#pragma unroll
        for (int nt = 0; nt < 4; nt++) {
            s16x8 bv = *(const s16x8*)(B + (size_t)nt * 16 * 1024 + k);
            acc[0][nt] = mfma16(a0, bv, acc[0][nt]);
            acc[1][nt] = mfma16(a1, bv, acc[1][nt]);
        }
    }
    float* os = oslice + (size_t)ks * 262144;
#pragma unroll
    for (int mt = 0; mt < 2; mt++)
#pragma unroll
        for (int nt = 0; nt < 4; nt++) {
            int e = nt * 16 + l15;
            int n0 = row0 + mt * 16 + quad * 4;
            float* o = os + (size_t)n0 * 64 + e;
#pragma unroll
            for (int r = 0; r < 4; r++) o[(size_t)r * 64] = acc[mt][nt][r];
        }
}

__global__ __launch_bounds__(256) void outred_kernel(
        const float* __restrict__ oslice, float* __restrict__ out) {
    int i = blockIdx.x * 256 + threadIdx.x;   // 262144 total
    out[i] = oslice[i] + oslice[i + 262144] + oslice[i + 524288] + oslice[i + 786432];
}

// ---- launch --------------------------------------------------------------

extern "C" void kernel_launch(void* const* d_in, const int* in_sizes, int n_in,
                              void* d_out, int out_size, void* d_ws, size_t ws_size,
                              hipStream_t stream) {
    const float* x  = (const float*)d_in[0];
    const float* Wq = (const float*)d_in[1];
    const float* bq = (const float*)d_in[2];
    const float* Wk = (const float*)d_in[3];
    const float* bk = (const float*)d_in[4];
    const float* Wv = (const float*)d_in[5];
    const float* bv = (const float*)d_in[6];
    const float* Ew = (const float*)d_in[7];
    const float* Eb = (const float*)d_in[8];
    const float* Fw = (const float*)d_in[9];
    const float* Fb = (const float*)d_in[10];
    const float* Wo = (const float*)d_in[11];

    char* ws = (char*)d_ws;
    u16*   qb   = (u16*)(ws + 0);          // H*N*E bf16            8 MB
    u16*   kT   = (u16*)(ws + 8388608);    // H*E*N bf16            8 MB
    u16*   vT   = (u16*)(ws + 16777216);   // H*E*N bf16            8 MB
    u16*   zsb  = (u16*)(ws + 25165824);   // N*(H*E) bf16          8 MB
    float* accs = (float*)(ws + 33554432); // 16 slices x 2 MB fp32 32 MB (reused as oslice)
    u16*   kp   = (u16*)(ws + 67108864);   // H*256*64 bf16       0.5 MB
    u16*   vpT  = (u16*)(ws + 67633152);   // H*64*256 bf16       0.5 MB
    u16*   xb   = (u16*)(ws + 68157440);   // N*D bf16              8 MB
    u16*   wb   = (u16*)(ws + 76546048);   // 3*H*E*D bf16          6 MB
    u16*   wob  = (u16*)(ws + 82837504);   // E*(H*E) bf16       128 KB

    cvt_all_kernel<<<7232, 256, 0, stream>>>(x, Wq, Wk, Wv, Wo, xb, wb, wob);
    qkv_kernel<<<768, 256, 0, stream>>>(xb, wb, bq, bk, bv, qb, kT, vT);
    kpvp_kernel<<<512, 256, 0, stream>>>(Ew, Fw, kT, vT, accs, 0);
    kpvp_kernel<<<512, 256, 0, stream>>>(Ew, Fw, kT, vT, accs, 8);
    packkv_kernel<<<256, 256, 0, stream>>>(accs, Eb, Fb, kp, vpT);
    attn_kernel<<<1024, 256, 0, stream>>>(qb, kp, vpT, zsb);
    out_kernel<<<128, 256, 0, stream>>>(zsb, wob, (float*)accs);   // accs free -> oslice
    outred_kernel<<<1024, 256, 0, stream>>>((const float*)accs, (float*)d_out);
}